// Round 2
// baseline (14587.474 us; speedup 1.0000x reference)
//
#include <hip/hip_runtime.h>
#include <hip/hip_bf16.h>
#include <hip/hip_fp16.h>

#define N_NODES 131072
#define N_EDGES 2097152
#define BSZ     4096
#define NREL    5
#define NBASIS  4

typedef unsigned int uint;
typedef unsigned short ushort;
typedef _Float16 v2h __attribute__((ext_vector_type(2)));
typedef __attribute__((ext_vector_type(8))) short bf16x8;
typedef __attribute__((ext_vector_type(4))) float f32x4;

__device__ __forceinline__ float bflo(uint u){ union{uint i;float f;}x; x.i = u<<16; return x.f; }
__device__ __forceinline__ float bf2f(ushort u){ return bflo((uint)u); }
__device__ __forceinline__ ushort f2bf(float f){
  union{float f;uint i;}x; x.f=f;
  uint r = (x.i + 0x7fffu + ((x.i>>16)&1u)) >> 16;
  return (ushort)r;
}
__device__ __forceinline__ float sigm(float x){ return 1.0f/(1.0f+__expf(-x)); }
__device__ __forceinline__ float tanh_fast(float x){
  x = fminf(fmaxf(x,-15.f),15.f);
  float e = __expf(2.0f*x);
  return (e-1.0f)/(e+1.0f);
}
__device__ __forceinline__ float dot2h(uint a, uint b, float c){
#if __has_builtin(__builtin_amdgcn_fdot2)
  return __builtin_amdgcn_fdot2(__builtin_bit_cast(v2h,a), __builtin_bit_cast(v2h,b), c, false);
#else
  v2h ah = __builtin_bit_cast(v2h,a), bh = __builtin_bit_cast(v2h,b);
  return c + (float)ah.x*(float)bh.x + (float)ah.y*(float)bh.y;
#endif
}

__global__ void k_cvt_half(const float* __restrict__ in, __half* __restrict__ out, int n){
  int i = blockIdx.x*256 + threadIdx.x;
  if (i < n) out[i] = __float2half(in[i]);
}
__global__ void k_cvt_bf(const float* __restrict__ in, ushort* __restrict__ out, int n){
  int i = blockIdx.x*256 + threadIdx.x;
  if (i < n) out[i] = f2bf(in[i]);
}

__global__ void k_count(const int* __restrict__ ei, const int* __restrict__ et, int* __restrict__ cnt){
  int e = blockIdx.x*256 + threadIdx.x;
  if (e < N_EDGES){
    int d = ei[N_EDGES + e];
    int r = et[e];
    atomicAdd(&cnt[d*NREL + r], 1);
  }
}
__global__ void k_inv(float* __restrict__ buf){
  int i = blockIdx.x*256 + threadIdx.x;
  if (i < N_NODES*NREL){
    int c = ((int*)buf)[i];
    buf[i] = (c > 0) ? (1.0f/(float)c) : 1.0f;
  }
}

// hb[n][j][b] = sum_i h[n,i]*basis[b,i,j], packed 4 bf16 per (n,j)
__global__ void k_hb(const float* __restrict__ x, const ushort* __restrict__ states, int l,
                     const float* __restrict__ basis_l, uint2* __restrict__ hb){
  __shared__ float bs[NBASIS*32*32];
  __shared__ float hs[256];
  int tid = threadIdx.x;
  #pragma unroll
  for (int r = 0; r < 16; r++){ int idx = r*256 + tid; bs[idx] = basis_l[idx]; }
  int nbase = blockIdx.x*8;
  if (l == 0){
    hs[tid] = x[nbase*32 + tid];
  } else {
    int n = nbase + (tid >> 5), i = tid & 31;
    hs[tid] = bf2f(states[n*128 + (l-1)*32 + i]);
  }
  __syncthreads();
  int nl = tid >> 5, j = tid & 31;
  float a0=0.f,a1=0.f,a2=0.f,a3=0.f;
  #pragma unroll
  for (int i = 0; i < 32; i++){
    float hv = hs[nl*32 + i];
    a0 += hv*bs[0*1024 + i*32 + j];
    a1 += hv*bs[1*1024 + i*32 + j];
    a2 += hv*bs[2*1024 + i*32 + j];
    a3 += hv*bs[3*1024 + i*32 + j];
  }
  uint2 o;
  o.x = (uint)f2bf(a0) | ((uint)f2bf(a1) << 16);
  o.y = (uint)f2bf(a2) | ((uint)f2bf(a3) << 16);
  hb[(nbase + nl)*32 + j] = o;
}

__global__ void k_edge(const int* __restrict__ ei, const int* __restrict__ et,
                       const float* __restrict__ comp_l, const float* __restrict__ inv,
                       const uint2* __restrict__ hb, float* __restrict__ agg){
  __shared__ float cl[NREL*NBASIS];
  int tid = threadIdx.x;
  if (tid < NREL*NBASIS) cl[tid] = comp_l[tid];
  __syncthreads();
  int e = blockIdx.x*8 + (tid >> 5);
  int j = tid & 31;
  int src = ei[e];
  int dst = ei[N_EDGES + e];
  int r = et[e];
  float nrm = inv[dst*NREL + r];
  uint2 v = hb[src*32 + j];
  float m = nrm*(cl[r*4+0]*bflo(v.x)       + cl[r*4+1]*bflo(v.x >> 16)
               + cl[r*4+2]*bflo(v.y)       + cl[r*4+3]*bflo(v.y >> 16));
  atomicAdd(&agg[dst*32 + j], m);
}

__global__ void k_combine(const float* __restrict__ agg, const float* __restrict__ x,
                          ushort* __restrict__ states, int l,
                          const float* __restrict__ root_l, const float* __restrict__ bias_l){
  __shared__ float rt[1024];
  __shared__ float hs[256];
  int tid = threadIdx.x;
  #pragma unroll
  for (int r = 0; r < 4; r++) rt[r*256 + tid] = root_l[r*256 + tid];
  int nbase = blockIdx.x*8;
  if (l == 0){
    hs[tid] = x[nbase*32 + tid];
  } else {
    int n = nbase + (tid >> 5), i = tid & 31;
    hs[tid] = bf2f(states[n*128 + (l-1)*32 + i]);
  }
  __syncthreads();
  int nl = tid >> 5, j = tid & 31;
  int n = nbase + nl;
  float acc = agg[n*32 + j] + bias_l[j];
  #pragma unroll
  for (int i = 0; i < 32; i++) acc += hs[nl*32 + i] * rt[i*32 + j];
  states[n*128 + l*32 + j] = f2bf(tanh_fast(acc));
}

__global__ void k_gather(const ushort* __restrict__ states, const int* __restrict__ uidx,
                         const int* __restrict__ vidx, ushort* __restrict__ z){
  int b = blockIdx.x;
  int k = threadIdx.x;                       // 256
  int node = (k < 128) ? uidx[b] : vidx[b];
  z[b*256 + k] = states[node*128 + (k & 127)];
}

__global__ void k_xgemm(const ushort* __restrict__ A, const ushort* __restrict__ W,
                        const float* __restrict__ bih, const float* __restrict__ bhh,
                        float* __restrict__ xg){
  int gw = blockIdx.x*4 + (threadIdx.x >> 6);
  int lane = threadIdx.x & 63;
  int t0 = (gw >> 6)*16;
  int j0 = (gw & 63)*16;
  int m = lane & 15, q = lane >> 4;
  const ushort* ap = A + (t0 + m)*256 + q*8;
  const ushort* bp = W + (j0 + m)*256 + q*8;
  f32x4 acc = {0.f,0.f,0.f,0.f};
  #pragma unroll
  for (int kk = 0; kk < 8; kk++){
    bf16x8 a = *(const bf16x8*)(ap + kk*32);
    bf16x8 b = *(const bf16x8*)(bp + kk*32);
    acc = __builtin_amdgcn_mfma_f32_16x16x32_bf16(a, b, acc, 0, 0, 0);
  }
  int j = j0 + m;
  float bias = bih[j] + bhh[j];
  #pragma unroll
  for (int r = 0; r < 4; r++){
    int t = t0 + q*4 + r;                    // C: col=lane&15, row=quad*4+reg (m89)
    xg[t*1024 + j] = acc[r] + bias;
  }
}

__launch_bounds__(512, 2)
__global__ void k_scan(const float* __restrict__ xg, const __half* __restrict__ whh,
                       ushort* __restrict__ outh){
  __shared__ uint hbuf[2][128];
  __shared__ float xch[2][256];
  __shared__ uint4 tl[512*16];               // 128 KB weight tail in LDS
  int t = threadIdx.x;
  const uint* wr0 = (const uint*)(whh + (size_t)t*256);
  const uint* wr1 = (const uint*)(whh + (size_t)(t+512)*256);
  uint w0[128];
  uint w1[64];
  #pragma unroll
  for (int k = 0; k < 128; k++) w0[k] = wr0[k];
  #pragma unroll
  for (int k = 0; k < 64; k++)  w1[k] = wr1[k];
  const uint4* wt = (const uint4*)(wr1 + 64);
  #pragma unroll
  for (int c = 0; c < 16; c++) tl[t*16 + ((c + t) & 15)] = wt[c];   // swizzle store
  if (t < 256) ((uint*)hbuf)[t] = 0u;
  float cst = 0.f;
  float px0 = xg[t], px1 = xg[t + 512];
  __syncthreads();
  for (int step = 0; step < 4096; step++){
    int cur = step & 1;
    float acc0a = px0, acc0b = 0.f, acc1a = px1, acc1b = 0.f;
    if (step < 4095){
      px0 = xg[(size_t)(step+1)*1024 + t];
      px1 = xg[(size_t)(step+1)*1024 + t + 512];
    }
    const uint4* h4p = (const uint4*)hbuf[cur];
    #pragma unroll
    for (int k4 = 0; k4 < 16; k4++){
      uint4 h4 = h4p[k4];                    // wave-uniform broadcast
      acc0a = dot2h(w0[4*k4+0], h4.x, acc0a);
      acc0b = dot2h(w0[4*k4+1], h4.y, acc0b);
      acc0a = dot2h(w0[4*k4+2], h4.z, acc0a);
      acc0b = dot2h(w0[4*k4+3], h4.w, acc0b);
      acc1a = dot2h(w1[4*k4+0], h4.x, acc1a);
      acc1b = dot2h(w1[4*k4+1], h4.y, acc1b);
      acc1a = dot2h(w1[4*k4+2], h4.z, acc1a);
      acc1b = dot2h(w1[4*k4+3], h4.w, acc1b);
    }
    #pragma unroll
    for (int k4 = 0; k4 < 16; k4++){
      uint4 h4 = h4p[16 + k4];
      uint4 wv = tl[t*16 + ((k4 + t) & 15)]; // swizzle load
      acc0a = dot2h(w0[64 + 4*k4+0], h4.x, acc0a);
      acc0b = dot2h(w0[64 + 4*k4+1], h4.y, acc0b);
      acc0a = dot2h(w0[64 + 4*k4+2], h4.z, acc0a);
      acc0b = dot2h(w0[64 + 4*k4+3], h4.w, acc0b);
      acc1a = dot2h(wv.x, h4.x, acc1a);
      acc1b = dot2h(wv.y, h4.y, acc1b);
      acc1a = dot2h(wv.z, h4.z, acc1a);
      acc1b = dot2h(wv.w, h4.w, acc1b);
    }
    float a0 = acc0a + acc0b, a1 = acc1a + acc1b;
    if (t >= 256){ xch[0][t-256] = a0; xch[1][t-256] = a1; }
    __syncthreads();
    if (t < 256){
      float iv = sigm(a0);                   // i
      float gv = tanh_fast(a1);              // g
      float fv = sigm(xch[0][t]);            // f
      float ov = sigm(xch[1][t]);            // o
      cst = fv*cst + iv*gv;
      float hv = ov*tanh_fast(cst);
      ((__half*)hbuf[cur ^ 1])[t] = __float2half(hv);
      outh[(size_t)step*256 + t] = f2bf(hv);
    }
    __syncthreads();
  }
}

__global__ void k_head1(const ushort* __restrict__ h, const float* __restrict__ w,
                        const float* __restrict__ b, float* __restrict__ out){
  __shared__ float s[256];
  int t = blockIdx.x, j = threadIdx.x;       // 128 threads
  s[j]       = bf2f(h[t*256 + j]);
  s[j + 128] = bf2f(h[t*256 + 128 + j]);
  __syncthreads();
  float acc = b[j];
  const float4* wr4 = (const float4*)(w + j*256);
  #pragma unroll
  for (int k4 = 0; k4 < 64; k4++){
    float4 v = wr4[k4];
    int k = k4*4;
    acc += s[k+0]*v.x + s[k+1]*v.y + s[k+2]*v.z + s[k+3]*v.w;
  }
  out[t*128 + j] = fmaxf(acc, 0.f);
}
__global__ void k_head2(const float* __restrict__ hm, const float* __restrict__ w,
                        const float* __restrict__ b, float* __restrict__ out){
  int t = blockIdx.x*256 + threadIdx.x;
  if (t < BSZ){
    float acc = b[0];
    #pragma unroll
    for (int k = 0; k < 128; k++) acc += hm[t*128 + k]*w[k];
    out[t] = acc;
  }
}

extern "C" void kernel_launch(void* const* d_in, const int* in_sizes, int n_in,
                              void* d_out, int out_size, void* d_ws, size_t ws_size,
                              hipStream_t stream){
  const float* x     = (const float*)d_in[0];
  const int*   ei    = (const int*)d_in[1];
  const int*   et    = (const int*)d_in[2];
  const int*   uidx  = (const int*)d_in[3];
  const int*   vidx  = (const int*)d_in[4];
  const float* basis = (const float*)d_in[5];
  const float* comp  = (const float*)d_in[6];
  const float* root  = (const float*)d_in[7];
  const float* cbias = (const float*)d_in[8];
  const float* w_ih  = (const float*)d_in[9];
  const float* w_hh  = (const float*)d_in[10];
  const float* b_ih  = (const float*)d_in[11];
  const float* b_hh  = (const float*)d_in[12];
  const float* lin1w = (const float*)d_in[13];
  const float* lin1b = (const float*)d_in[14];
  const float* lin2w = (const float*)d_in[15];
  const float* lin2b = (const float*)d_in[16];

  char* ws = (char*)d_ws;
  __half* whh16  = (__half*)(ws + 0);                 // 1 MB
  ushort* wihbf  = (ushort*)(ws + 1048576);           // 1 MB
  float*  inv    = (float*) (ws + 2097152);           // 2.5 MB
  ushort* states = (ushort*)(ws + 4718592);           // 32 MB
  char*   scr    = ws + 38273024;                     // 48 MB scratch union (total ~84.5 MB)
  uint2*  hb     = (uint2*)(scr);                     // GNN: 32 MB
  float*  agg    = (float*)(scr + 33554432);          // GNN: 16 MB
  ushort* z      = (ushort*)(scr + 0);                // LSTM phase aliases
  ushort* out1   = (ushort*)(scr + 2097152);
  ushort* out2   = (ushort*)(scr + 4194304);
  float*  hmid   = (float*) (scr + 6291456);
  float*  xg     = (float*) (scr + 8388608);

  k_cvt_half<<<2048, 256, 0, stream>>>(w_hh, whh16, 2*1024*256);
  k_cvt_bf  <<<2048, 256, 0, stream>>>(w_ih, wihbf, 2*1024*256);
  hipMemsetAsync(inv, 0, (size_t)N_NODES*NREL*4, stream);
  k_count<<<N_EDGES/256, 256, 0, stream>>>(ei, et, (int*)inv);
  k_inv<<<(N_NODES*NREL)/256, 256, 0, stream>>>(inv);

  for (int l = 0; l < 4; l++){
    k_hb<<<N_NODES/8, 256, 0, stream>>>(x, states, l, basis + l*NBASIS*1024, hb);
    hipMemsetAsync(agg, 0, (size_t)N_NODES*32*4, stream);
    k_edge<<<N_EDGES/8, 256, 0, stream>>>(ei, et, comp + l*NREL*NBASIS, inv, hb, agg);
    k_combine<<<N_NODES/8, 256, 0, stream>>>(agg, x, states, l, root + l*1024, cbias + l*32);
  }

  k_gather<<<BSZ, 256, 0, stream>>>(states, uidx, vidx, z);
  k_xgemm<<<4096, 256, 0, stream>>>(z,    wihbf,          b_ih,        b_hh,        xg);
  k_scan <<<1, 512, 0, stream>>>(xg, whh16,          out1);
  k_xgemm<<<4096, 256, 0, stream>>>(out1, wihbf + 262144, b_ih + 1024, b_hh + 1024, xg);
  k_scan <<<1, 512, 0, stream>>>(xg, whh16 + 262144, out2);
  k_head1<<<BSZ, 128, 0, stream>>>(out2, lin1w, lin1b, hmid);
  k_head2<<<BSZ/256, 256, 0, stream>>>(hmid, lin2w, lin2b, (float*)d_out);
}